// Round 13
// baseline (306.319 us; speedup 1.0000x reference)
//
#include <hip/hip_runtime.h>
#include <cmath>

typedef unsigned short u16;
typedef float floatx4 __attribute__((ext_vector_type(4)));
typedef short short8 __attribute__((ext_vector_type(8)));
typedef short short4v __attribute__((ext_vector_type(4)));
typedef __bf16 bf16x8 __attribute__((ext_vector_type(8)));

#define GLOBAL_AS __attribute__((address_space(1)))
#define LDS_AS __attribute__((address_space(3)))

#define S_LEN 2048
#define D_MODEL 2048
#define NH 16
#define NKV 4
#define DHEAD 128
#define SM_SCALE 0.08838834764831843f
#define K2 (SM_SCALE * 1.4426950408889634f) /* SM_SCALE * log2(e) */

__device__ __forceinline__ u16 f2bf(float f) {
    unsigned int u = __builtin_bit_cast(unsigned int, f);
    u += 0x7fffu + ((u >> 16) & 1u);
    return (u16)(u >> 16);
}
__device__ __forceinline__ u16 f2bfr(float f) {
    unsigned int u = __builtin_bit_cast(unsigned int, f);
    return (u16)((u + 0x8000u) >> 16);
}
__device__ __forceinline__ float bf2f(u16 x) {
    unsigned int u = ((unsigned int)x) << 16;
    return __builtin_bit_cast(float, u);
}
__device__ __forceinline__ floatx4 zf4() {
    floatx4 z; z[0] = 0.f; z[1] = 0.f; z[2] = 0.f; z[3] = 0.f; return z;
}
__device__ __forceinline__ floatx4 mfma16(short8 a, short8 b, floatx4 c) {
    return __builtin_amdgcn_mfma_f32_16x16x32_bf16(
        __builtin_bit_cast(bf16x8, a), __builtin_bit_cast(bf16x8, b), c, 0, 0, 0);
}
__device__ __forceinline__ floatx4 mfma16k16(short4v a, short4v b, floatx4 c) {
    return __builtin_amdgcn_mfma_f32_16x16x16bf16_1k(a, b, c, 0, 0, 0);
}
__device__ __forceinline__ void async16(const u16* g, u16* l) {
    __builtin_amdgcn_global_load_lds((GLOBAL_AS void*)g, (LDS_AS void*)l, 16, 0, 0);
}

// ---------------- fused prologue: cast X, rope tables, weight transposes (one launch) ----------------
__global__ void prologue_kernel(const float4* __restrict__ Xin, ushort4* __restrict__ Xout,
                                float* __restrict__ cs_tab, float* __restrict__ sn_tab,
                                const float* __restrict__ wq, const float* __restrict__ wk,
                                const float* __restrict__ wv, const float* __restrict__ wo,
                                u16* __restrict__ Wqkv, u16* __restrict__ Wo) {
    __shared__ float tile[32][33];
    int bid = blockIdx.x;
    if (bid < 8192) {
        int i = bid * 256 + threadIdx.x;
        float4 v = Xin[i];
        ushort4 o;
        o.x = f2bf(v.x); o.y = f2bf(v.y); o.z = f2bf(v.z); o.w = f2bf(v.w);
        Xout[i] = o;
        return;
    }
    if (bid < 8704) {
        int idx = (bid - 8192) * 256 + threadIdx.x;  // 2048*64
        int p = idx >> 6, jj = idx & 63;
        double e = (double)(2 * jj) / 128.0;
        double invf = pow(10000.0, -e);
        float arg = (float)p * (float)invf;  // match reference's fp32 angle
        cs_tab[idx] = (float)cos((double)arg);
        sn_tab[idx] = (float)sin((double)arg);
        return;
    }
    int tb = bid - 8704;                 // 0..10239 = 160 x-chunks * 64 y-chunks
    int x = tb % 160, y = tb / 160;
    const float* in; u16* out; int C, bx;
    if (x < 64)      { in = wq; out = Wqkv;                     C = 2048; bx = x * 32; }
    else if (x < 80) { in = wk; out = Wqkv + (size_t)2048*2048; C = 512;  bx = (x - 64) * 32; }
    else if (x < 96) { in = wv; out = Wqkv + (size_t)2560*2048; C = 512;  bx = (x - 80) * 32; }
    else             { in = wo; out = Wo;                       C = 2048; bx = (x - 96) * 32; }
    const int R = 2048;
    int tx = threadIdx.x & 31, ty = threadIdx.x >> 5;
    int by = y * 32;
#pragma unroll
    for (int i = 0; i < 32; i += 8)
        tile[ty + i][tx] = in[(size_t)(by + ty + i) * C + bx + tx];
    __syncthreads();
#pragma unroll
    for (int i = 0; i < 32; i += 8)
        out[(size_t)(bx + ty + i) * R + by + tx] = f2bf(tile[tx][ty + i]);
}

// ---------------- apply RoPE in place on K only (Q rope is fused into fa) ----------------
__global__ void rope_k_kernel(u16* __restrict__ Kb, const int* __restrict__ pos,
                              const float4* __restrict__ cs_tab,
                              const float4* __restrict__ sn_tab) {
    int idx = blockIdx.x * 256 + threadIdx.x;  // 2*4*2048*16 = 262144
    int j4 = idx & 15;
    int s = (idx >> 4) & 2047;
    int r = idx >> 15;        // b*4 + hh
    int hh = r & 3, b = r >> 2;
    int p = pos[b * S_LEN + s];
    float4 cs = cs_tab[p * 16 + j4];
    float4 sn = sn_tab[p * 16 + j4];
    u16* base = Kb + (((size_t)(b * NKV + hh)) * S_LEN + s) * DHEAD + j4 * 4;
    ushort4 a = *(const ushort4*)(base);
    ushort4 c = *(const ushort4*)(base + 64);
    ushort4 oa, oc;
    float x1, x2;
    x1 = bf2f(a.x); x2 = bf2f(c.x); oa.x = f2bf(x1 * cs.x - x2 * sn.x); oc.x = f2bf(x2 * cs.x + x1 * sn.x);
    x1 = bf2f(a.y); x2 = bf2f(c.y); oa.y = f2bf(x1 * cs.y - x2 * sn.y); oc.y = f2bf(x2 * cs.y + x1 * sn.y);
    x1 = bf2f(a.z); x2 = bf2f(c.z); oa.z = f2bf(x1 * cs.z - x2 * sn.z); oc.z = f2bf(x2 * cs.z + x1 * sn.z);
    x1 = bf2f(a.w); x2 = bf2f(c.w); oa.w = f2bf(x1 * cs.w - x2 * sn.w); oc.w = f2bf(x2 * cs.w + x1 * sn.w);
    *(ushort4*)(base) = oa;
    *(ushort4*)(base + 64) = oc;
}

// ---------------- GEMM mainloop: 128x256 block, 4 waves (2x2), per-wave 64x128 ----------------
// Same r3-proven 2-barrier/XOR-swizzle structure, widened: per K-tile per wave
// 24 ds_read_b128 feed 64 MFMA (ratio 2.67 vs 2.0 at 128^2).  LDS bytes per
// unit work: (48 staged + 96 read)/2 = 72 KB vs 96 KB at 128^2 -> -25% on the
// LDS port, which the r7/r9/r10 invariance (pipeline changes moved FETCH but
// not time) identifies as the binding resource.  LDS 48 KB -> 2 blocks/CU
// co-resident (m114 inter-block overlap preserved).  VGPR ~200-230 under the
// launch_bounds(256,2) cap of 256 -> no spill (watch WRITE_SIZE).
__device__ __forceinline__ void gemm_mainloop(const u16* __restrict__ A,
                                              const u16* __restrict__ Bt,
                                              int K, u16* ldsA, u16* ldsB,
                                              floatx4 acc[4][8], int m0, int n0) {
    const int t = threadIdx.x;
    const int lane = t & 63, wave = t >> 6;
    const int wr = wave >> 1, wc = wave & 1;
    const int lr = lane & 15, q = lane >> 4;
    const int swz = lr & 7;

#pragma unroll
    for (int r = 0; r < 4; ++r)
#pragma unroll
        for (int c = 0; c < 8; ++c) acc[r][c] = zf4();

    for (int k0 = 0; k0 < K; k0 += 64) {
        // stage A (128x64: 1024 chunks / 256 thr = 4) + B (256x64: 2048 / 256 = 8)
#pragma unroll
        for (int i = 0; i < 4; ++i) {
            int ci = i * 256 + t;
            int row = ci >> 3;
            int kc = ((ci & 7) ^ (row & 7)) << 3;
            async16(A + (size_t)(m0 + row) * K + k0 + kc, ldsA + (i * 256 + wave * 64) * 8);
        }
#pragma unroll
        for (int i = 0; i < 8; ++i) {
            int ci = i * 256 + t;
            int row = ci >> 3;
            int kc = ((ci & 7) ^ (row & 7)) << 3;
            async16(Bt + (size_t)(n0 + row) * K + k0 + kc, ldsB + (i * 256 + wave * 64) * 8);
        }
        __syncthreads();
#pragma unroll
        for (int ks = 0; ks < 2; ++ks) {
            short8 af[4], bfr[8];
#pragma unroll
            for (int r = 0; r < 4; ++r)
                af[r] = *(const short8*)(ldsA + (wr * 64 + r * 16 + lr) * 64 +
                                         (((ks * 4 + q) ^ swz) << 3));
#pragma unroll
            for (int c = 0; c < 8; ++c)
                bfr[c] = *(const short8*)(ldsB + (wc * 128 + c * 16 + lr) * 64 +
                                          (((ks * 4 + q) ^ swz) << 3));
#pragma unroll
            for (int r = 0; r < 4; ++r)
#pragma unroll
                for (int c = 0; c < 8; ++c)
                    acc[r][c] = mfma16(af[r], bfr[c], acc[r][c]);
        }
        __syncthreads();
    }
}

// ---------------- QKV GEMM (128x256, XCD-grouped 1-D grid 384) ----------------
// xcd = bid&7; slot = bid>>3 (0..47): y = 4*xcd + slot/12 (A-panel), x = slot%12.
__global__ __launch_bounds__(256, 2) void qkv_gemm_kernel(const u16* __restrict__ A,
                                                          const u16* __restrict__ Bt,
                                                          u16* __restrict__ Qb,
                                                          u16* __restrict__ Kb,
                                                          u16* __restrict__ Vt) {
    __shared__ u16 ldsA[128 * 64];
    __shared__ u16 ldsB[256 * 64];
    const int xcd = blockIdx.x & 7, slot = blockIdx.x >> 3;
    const int by = 4 * xcd + slot / 12, bx = slot % 12;
    const int m0 = by * 128, n0 = bx * 256;

    floatx4 acc[4][8];
    gemm_mainloop(A, Bt, D_MODEL, ldsA, ldsB, acc, m0, n0);

    const int t = threadIdx.x, lane = t & 63, wave = t >> 6;
    const int wr = wave >> 1, wc = wave & 1, lr = lane & 15, q = lane >> 4;
    const int em0 = m0 + wr * 64, en0 = n0 + wc * 128;
#pragma unroll
    for (int r = 0; r < 4; ++r)
#pragma unroll
        for (int c = 0; c < 8; ++c) {
            int gc = en0 + c * 16 + lr;
#pragma unroll
            for (int rr = 0; rr < 4; ++rr) {
                int grow = em0 + r * 16 + q * 4 + rr;  // token
                int bb = grow >> 11, s = grow & 2047;
                u16 bv = f2bf(acc[r][c][rr]);
                int d = gc & 127;
                if (gc < 2048) {
                    int hh = gc >> 7;
                    Qb[(((size_t)(bb * NH + hh)) * S_LEN + s) * DHEAD + d] = bv;
                } else if (gc < 2560) {
                    int hh = (gc - 2048) >> 7;
                    Kb[(((size_t)(bb * NKV + hh)) * S_LEN + s) * DHEAD + d] = bv;
                } else {
                    int hh = (gc - 2560) >> 7;
                    int s2 = s ^ ((d & 8) >> 1);  // V half-spread (fa's b64 V reads)
                    Vt[(((size_t)(bb * NKV + hh)) * DHEAD + d) * S_LEN + s2] = bv;
                }
            }
        }
}

// ---------------- out GEMM (128x256, XCD-grouped 1-D grid 256) ----------------
// xcd = bid&7; slot = bid>>3 (0..31): y = 4*xcd + slot/8, x = slot%8.
__global__ __launch_bounds__(256, 2) void out_gemm_kernel(const u16* __restrict__ A,
                                                          const u16* __restrict__ Bt,
                                                          float* __restrict__ out) {
    __shared__ u16 ldsA[128 * 64];
    __shared__ u16 ldsB[256 * 64];
    const int xcd = blockIdx.x & 7, slot = blockIdx.x >> 3;
    const int by = 4 * xcd + slot / 8, bx = slot & 7;
    const int m0 = by * 128, n0 = bx * 256;

    floatx4 acc[4][8];
    gemm_mainloop(A, Bt, D_MODEL, ldsA, ldsB, acc, m0, n0);

    const int t = threadIdx.x, lane = t & 63, wave = t >> 6;
    const int wr = wave >> 1, wc = wave & 1, lr = lane & 15, q = lane >> 4;
    const int em0 = m0 + wr * 64, en0 = n0 + wc * 128;
#pragma unroll
    for (int r = 0; r < 4; ++r)
#pragma unroll
        for (int c = 0; c < 8; ++c) {
            int gc = en0 + c * 16 + lr;
#pragma unroll
            for (int rr = 0; rr < 4; ++rr) {
                int grow = em0 + r * 16 + q * 4 + rr;
                out[(size_t)grow * D_MODEL + gc] = acc[r][c][rr];
            }
        }
}

// ---------------- flash attention (r3 version, best measured: 85.2 us) ----------------
__global__ __launch_bounds__(256, 2) void fa_kernel(const u16* __restrict__ Qb,
                                                    const u16* __restrict__ Kb,
                                                    const u16* __restrict__ Vt,
                                                    u16* __restrict__ Ob,
                                                    const int* __restrict__ pos,
                                                    const float4* __restrict__ cs_tab,
                                                    const float4* __restrict__ sn_tab) {
    __shared__ u16 ldsK[2][64 * 128];
    __shared__ u16 ldsV[2][128 * 64];

    const int t = threadIdx.x, lane = t & 63, wave = t >> 6;
    const int lr = lane & 15, q = lane >> 4;
    const int swz = lr & 7;

    const int bid = blockIdx.x;
    const int bh = bid >> 4, p = bid & 15;
    const int qt0 = p, qt1 = 31 - p;
    const int b = bh >> 4, h = bh & 15;
    const int kvh = h >> 2;

    const u16* Kp = Kb + (size_t)(b * NKV + kvh) * S_LEN * DHEAD;
    const u16* Vp = Vt + (size_t)(b * NKV + kvh) * DHEAD * S_LEN;

    short8 qf0[4], qf1[4];
    auto load_rope_q = [&](int qt, short8 (&qf)[4]) {
        const u16* Qp = Qb + ((size_t)((b * NH + h) * S_LEN) + qt * 64 + wave * 16) * DHEAD;
#pragma unroll
        for (int kk = 0; kk < 4; ++kk)
            qf[kk] = *(const short8*)(Qp + (size_t)lr * DHEAD + kk * 32 + q * 8);
        const int srow = qt * 64 + wave * 16 + lr;
        const int pp = pos[b * S_LEN + srow];
#pragma unroll
        for (int kk = 0; kk < 2; ++kk)
#pragma unroll
            for (int h4 = 0; h4 < 2; ++h4) {
                float4 cs = cs_tab[pp * 16 + kk * 8 + q * 2 + h4];
                float4 sn = sn_tab[pp * 16 + kk * 8 + q * 2 + h4];
#pragma unroll
                for (int e = 0; e < 4; ++e) {
                    float cc = (&cs.x)[e], ss = (&sn.x)[e];
                    int ei = h4 * 4 + e;
                    float x1 = bf2f((u16)qf[kk][ei]);
                    float x2 = bf2f((u16)qf[kk + 2][ei]);
                    qf[kk][ei]     = (short)f2bf(x1 * cc - x2 * ss);
                    qf[kk + 2][ei] = (short)f2bf(x2 * cc + x1 * ss);
                }
            }
    };
    load_rope_q(qt0, qf0);
    load_rope_q(qt1, qf1);

    auto stage = [&](int kt, int bs) {
#pragma unroll
        for (int i = 0; i < 4; ++i) {
            int ci = i * 256 + t;
            int krow = ci >> 4, kc = ((ci & 15) ^ ((ci >> 4) & 7)) << 3;
            async16(Kp + (size_t)(kt * 64 + krow) * DHEAD + kc,
                    &ldsK[bs][(i * 256 + wave * 64) * 8]);
            int dh = ci >> 3, vc = ((ci & 7) ^ ((ci >> 3) & 7)) << 3;
            async16(Vp + (size_t)dh * S_LEN + kt * 64 + vc,
                    &ldsV[bs][(i * 256 + wave * 64) * 8]);
        }
    };

    floatx4 accO[8];
    float m_i, l_i;

    auto do_tile = [&](int kt, int qt_c, const short8 (&qfc)[4], int bs) {
        floatx4 sc[4];
        __builtin_amdgcn_s_setprio(1);
#pragma unroll
        for (int c = 0; c < 4; ++c) {
            sc[c] = zf4();
#pragma unroll
            for (int kk = 0; kk < 4; ++kk) {
                short8 kfr = *(const short8*)(&ldsK[bs][(c * 16 + lr) * DHEAD +
                                              (((kk * 4 + q) ^ swz) << 3)]);
                sc[c] = mfma16(kfr, qfc[kk], sc[c]);
            }
        }
        __builtin_amdgcn_s_setprio(0);

        if (kt == qt_c) {
            const int qrow = wave * 16 + lr;
#pragma unroll
            for (int c = 0; c < 4; ++c)
#pragma unroll
                for (int rr = 0; rr < 4; ++rr)
                    if (c * 16 + q * 4 + rr > qrow) sc[c][rr] = -3e38f;
        }

        float mx = -3e38f;
#pragma unroll
        for (int c = 0; c < 4; ++c)
#pragma unroll
            for (int rr = 0; rr < 4; ++rr) mx = fmaxf(mx, sc[c][rr]);
        mx = fmaxf(mx, __shfl_xor(mx, 16));
        mx = fmaxf(mx, __shfl_xor(mx, 32));
        float mnew = fmaxf(m_i, mx);
        float mk = mnew * K2;
        bool anyup = __any(mnew > m_i);
        float rs = 0.f;
#pragma unroll
        for (int c = 0; c < 4; ++c)
#pragma unroll
            for (int rr = 0; rr < 4; ++rr) {
                float pe = __builtin_amdgcn_exp2f(fmaf(sc[c][rr], K2, -mk));
                sc[c][rr] = pe;
                rs += pe;
            }
        rs += __shfl_xor(rs, 16);
        rs += __shfl_xor(rs, 32);
        if (anyup) {
            float alpha = __builtin_amdgcn_exp2f(fmaf(m_i, K2, -mk));
            l_i = l_i * alpha + rs;
#pragma unroll
            for (int d = 0; d < 8; ++d) accO[d] *= alpha;
        } else {
            l_i += rs;
        }
        m_i = mnew;

        short4v pb[4];
#pragma unroll
        for (int c = 0; c < 4; ++c) {
            pb[c][0] = (short)f2bfr(sc[c][0]);
            pb[c][1] = (short)f2bfr(sc[c][1]);
            pb[c][2] = (short)f2bfr(sc[c][2]);
            pb[c][3] = (short)f2bfr(sc[c][3]);
        }

        __builtin_amdgcn_s_setprio(1);
#pragma unroll
        for (int ks = 0; ks < 4; ++ks)
#pragma unroll
            for (int d = 0; d < 8; ++d) {
                short4v vf = *(const short4v*)(&ldsV[bs][(d * 16 + lr) * 64 +
                                               (((ks * 2 + (q >> 1)) ^ swz) << 3) +
                                               (((q ^ (lr >> 3)) & 1) << 2)]);
                accO[d] = mfma16k16(vf, pb[ks], accO[d]);
            }
        __builtin_amdgcn_s_setprio(0);
    };

    auto epilogue = [&](int qt_c) {
        const int tok = qt_c * 64 + wave * 16 + lr;
        const float inv = 1.0f / l_i;
        u16* orow = Ob + ((size_t)(b * S_LEN + tok)) * (NH * DHEAD) + h * DHEAD + q * 4;
#pragma unroll
        for (int d = 0; d < 8; ++d) {
            ushort4 o;
            o.x = f2bf(accO[d][0] * inv);
            o.y = f2bf(accO[d][1] * inv);
            o.z = f2bf(accO[d][2] * inv);
            o.w = f2bf(accO[d][3] * inv);
            *(ushort4*)(orow + d * 16) = o;
        }
    };

#pragma unroll
    for (int d = 0; d < 8; ++d) accO[d] = zf4();
    m_i = -3e38f; l_i = 0.f;

    int cur = 0;
    stage(0, 0);
    __syncthreads();

    for (int kt = 0; kt <= qt0; ++kt) {
        int nxt = cur ^ 1;
        int nk = (kt < qt0) ? kt + 1 : 0;  // last tile prefetches seg-1 kt=0
        stage(nk, nxt);
        do_tile(kt, qt0, qf0, cur);
        __syncthreads();
        cur = nxt;
    }
    epilogue(qt0);
#pragma unroll
    for (int d = 0; d < 8; ++d) accO[d] = zf4();
    m_i = -3e38f; l_i = 0.f;

    for (int kt = 0; kt <= qt1; ++kt) {
        int nxt = cur ^ 1;
        if (kt < qt1) stage(kt + 1, nxt);
        do_tile(kt, qt1, qf1, cur);
        __syncthreads();
        cur = nxt;
    }
    epilogue(qt1);
}

extern "C" void kernel_launch(void* const* d_in, const int* in_sizes, int n_in,
                              void* d_out, int out_size, void* d_ws, size_t ws_size,
                              hipStream_t stream) {
    const float* X  = (const float*)d_in[0];
    const int* pos  = (const int*)d_in[1];
    const float* wq = (const float*)d_in[2];
    const float* wk = (const float*)d_in[3];
    const float* wv = (const float*)d_in[4];
    const float* wo = (const float*)d_in[5];
    float* out = (float*)d_out;

    char* w = (char*)d_ws;
    u16* Xbf    = (u16*)(w);                    // 4096*2048*2      = 16777216
    u16* Wqkv   = (u16*)(w + 16777216);         // 3072*2048*2      = 12582912
    u16* Wo     = (u16*)(w + 29360128);         // 2048*2048*2      =  8388608
    u16* Qb     = (u16*)(w + 37748736);         // 2*16*2048*128*2  = 16777216
    u16* Kb     = (u16*)(w + 54525952);         // 2*4*2048*128*2   =  4194304
    u16* Vt     = (u16*)(w + 58720256);         //                  =  4194304
    u16* Ob     = (u16*)(w + 62914560);         // 4096*2048*2      = 16777216
    float* cst  = (float*)(w + 79691776);       // 2048*64*4        =   524288
    float* snt  = (float*)(w + 80216064);       //                  =   524288

    prologue_kernel<<<18944, 256, 0, stream>>>((const float4*)X, (ushort4*)Xbf, cst, snt,
                                               wq, wk, wv, wo, Wqkv, Wo);
    qkv_gemm_kernel<<<384, 256, 0, stream>>>(Xbf, Wqkv, Qb, Kb, Vt);
    rope_k_kernel<<<1024, 256, 0, stream>>>(Kb, pos, (const float4*)cst, (const float4*)snt);
    fa_kernel<<<512, 256, 0, stream>>>(Qb, Kb, Vt, Ob, pos, (const float4*)cst, (const float4*)snt);
    out_gemm_kernel<<<256, 256, 0, stream>>>(Ob, Wo, out);
}